// Round 6
// baseline (532.818 us; speedup 1.0000x reference)
//
#include <hip/hip_runtime.h>
#include <hip/hip_bf16.h>

#define BB 4
#define CC 256
#define NN 4096
#define SS 3
#define C8 32
#define L2E 1.4426950408889634f

typedef __attribute__((ext_vector_type(8))) short short8;
typedef __attribute__((ext_vector_type(4))) float floatx4;

static __device__ inline unsigned pack_bf16(float a, float b) {  // RNE (projections)
  union { __hip_bfloat16 h; unsigned short u; } ua, ub;
  ua.h = __float2bfloat16(a);
  ub.h = __float2bfloat16(b);
  return ((unsigned)ub.u << 16) | (unsigned)ua.u;
}

static __device__ inline unsigned pack_bf16_fast(float a, float b) {  // round-half-up (P only)
  unsigned ua = __float_as_uint(a), ub = __float_as_uint(b);
  return ((ua + 0x8000u) >> 16) | ((ub + 0x8000u) & 0xffff0000u);
}

static __device__ inline float fast_exp2(float x) {
#if __has_builtin(__builtin_amdgcn_exp2f)
  return __builtin_amdgcn_exp2f(x);
#else
  return exp2f(x);
#endif
}

// ---------------------------------------------------------------------------
// K1 pre: z<4: xfT[z][n][c] = bf16(x_f[z][c][n])  (64x64 LDS transpose)
//         z==4: zero outs + weights fp32->bf16 (Wq scaled by log2e)
// ---------------------------------------------------------------------------
__global__ void __launch_bounds__(256) pre_kernel(
    const float* __restrict__ xf, __hip_bfloat16* __restrict__ xfT,
    float4* __restrict__ outs4, const float* __restrict__ Wq,
    const float* __restrict__ Wk, const float* __restrict__ Wv,
    const float* __restrict__ Wf, __hip_bfloat16* __restrict__ WqB,
    __hip_bfloat16* __restrict__ WkB, __hip_bfloat16* __restrict__ WvB,
    __hip_bfloat16* __restrict__ WfB) {
  const int z = blockIdx.z, t = threadIdx.x;
  if (z < 4) {
    __shared__ float ts[64][65];
    const int c0 = blockIdx.y * 64, n0 = blockIdx.x * 64;
    const float* Xg = xf + ((size_t)z * CC + c0) * NN + n0;
    for (int idx = t; idx < 64 * 64; idx += 256) {
      int r = idx >> 6, qq = idx & 63;
      ts[r][qq] = Xg[(size_t)r * NN + qq];
    }
    __syncthreads();
    __hip_bfloat16* og = xfT + (size_t)z * NN * CC + (size_t)n0 * CC + c0;
    for (int idx = t; idx < 64 * 32; idx += 256) {
      int n = idx >> 5, pc = idx & 31;
      ((unsigned*)(og + (size_t)n * CC))[pc] =
          pack_bf16(ts[2 * pc][n], ts[2 * pc + 1][n]);
    }
  } else {
    const int wb = blockIdx.y * 64 + blockIdx.x;  // 0..255
    float4 zq = {0.f, 0.f, 0.f, 0.f};
#pragma unroll
    for (int k = 0; k < 16; ++k) outs4[(size_t)wb * 4096 + k * 256 + t] = zq;
#pragma unroll
    for (int k = 0; k < 4; ++k) {
      int idx = wb * 1024 + k * 256 + t;
      if (idx < 8192) WqB[idx] = __float2bfloat16(Wq[idx] * L2E);
      else if (idx < 16384) WkB[idx - 8192] = __float2bfloat16(Wk[idx - 8192]);
      else if (idx < 81920) WvB[idx - 16384] = __float2bfloat16(Wv[idx - 16384]);
      else if (idx < 212992) WfB[idx - 81920] = __float2bfloat16(Wf[idx - 81920]);
    }
  }
}

// ---------------------------------------------------------------------------
// K2 qkv: z<12 -> g=z: stage x_b[g][:, n0:n0+64] fp32 -> LDS bf16 [n][c],
//   then MFMA: vB[g] (Wv, all waves, c-split) and qT[g] (Wq, wave->n-quarter).
// z>=12 -> b=z-12: kT[b] from xfT rows (direct global B-frags, no LDS).
// x_b is read exactly ONCE from HBM (no xbT intermediate).
// ---------------------------------------------------------------------------
__global__ void __launch_bounds__(256) qkv_kernel(
    const float* __restrict__ xb, const __hip_bfloat16* __restrict__ xfT,
    const __hip_bfloat16* __restrict__ WqB, const __hip_bfloat16* __restrict__ WkB,
    const __hip_bfloat16* __restrict__ WvB, const float* __restrict__ bq,
    const float* __restrict__ bk, const float* __restrict__ bv,
    __hip_bfloat16* __restrict__ qT, __hip_bfloat16* __restrict__ kT,
    __hip_bfloat16* __restrict__ vB) {
  __shared__ unsigned xs32[64][129];  // [n][c-pair] bf16x2, +1 dword pad
  const int z = blockIdx.y, n0 = blockIdx.x * 64;
  const int t = threadIdx.x, w = t >> 6, lane = t & 63;
  const int q = lane >> 4, li = lane & 15;
  floatx4 zf = {0.f, 0.f, 0.f, 0.f};

  if (z < 12) {
    const int g = z;
    // ---- stage: read x_b [c][n] fp32 coalesced, write LDS [n][c] bf16 ----
    const float* Xg = xb + (size_t)g * CC * NN + n0;
    const int n4 = (t & 15) * 4, pb = t >> 4;
#pragma unroll
    for (int m = 0; m < 8; ++m) {
      int p = pb + m * 16;          // c-pair 0..127
      int c = 2 * p;
      float4 a = *(const float4*)(Xg + (size_t)c * NN + n4);
      float4 bq4 = *(const float4*)(Xg + (size_t)(c + 1) * NN + n4);
      xs32[n4 + 0][p] = pack_bf16(a.x, bq4.x);
      xs32[n4 + 1][p] = pack_bf16(a.y, bq4.y);
      xs32[n4 + 2][p] = pack_bf16(a.z, bq4.z);
      xs32[n4 + 3][p] = pack_bf16(a.w, bq4.w);
    }
    __syncthreads();
    // ---- V: wave w -> c-out strip w*64, all 4 n-tiles ----
    const int o_w = w * 64;
    floatx4 acc[4][4];
#pragma unroll
    for (int ot = 0; ot < 4; ++ot)
#pragma unroll
      for (int nt = 0; nt < 4; ++nt) acc[ot][nt] = zf;
#pragma unroll
    for (int kc = 0; kc < 8; ++kc) {
      short8 a[4], bfr[4];
#pragma unroll
      for (int ot = 0; ot < 4; ++ot)
        a[ot] = *(const short8*)(WvB + (size_t)(o_w + ot * 16 + li) * CC + kc * 32 + q * 8);
#pragma unroll
      for (int nt = 0; nt < 4; ++nt)
        bfr[nt] = *(const short8*)&xs32[nt * 16 + li][kc * 16 + q * 4];
#pragma unroll
      for (int ot = 0; ot < 4; ++ot)
#pragma unroll
        for (int nt = 0; nt < 4; ++nt)
          acc[ot][nt] = __builtin_amdgcn_mfma_f32_16x16x32_bf16(a[ot], bfr[nt],
                                                                acc[ot][nt], 0, 0, 0);
    }
    __hip_bfloat16* dst = vB + (size_t)g * CC * NN;
#pragma unroll
    for (int ot = 0; ot < 4; ++ot)
#pragma unroll
      for (int r = 0; r < 4; ++r) {
        int o = o_w + ot * 16 + q * 4 + r;
        float bo = bv[o];
#pragma unroll
        for (int nt = 0; nt < 4; ++nt)
          dst[(size_t)o * NN + n0 + nt * 16 + li] =
              __float2bfloat16(acc[ot][nt][r] + bo);
      }
    // ---- Q: wave w -> n-tile w ----
    floatx4 acq[2];
    acq[0] = zf; acq[1] = zf;
#pragma unroll
    for (int kc = 0; kc < 8; ++kc) {
      short8 bfr = *(const short8*)&xs32[w * 16 + li][kc * 16 + q * 4];
#pragma unroll
      for (int ot = 0; ot < 2; ++ot) {
        short8 a = *(const short8*)(WqB + (size_t)(ot * 16 + li) * CC + kc * 32 + q * 8);
        acq[ot] = __builtin_amdgcn_mfma_f32_16x16x32_bf16(a, bfr, acq[ot], 0, 0, 0);
      }
    }
    __hip_bfloat16* qdst = qT + (size_t)g * NN * C8;
    int n = n0 + w * 16 + li;
#pragma unroll
    for (int ot = 0; ot < 2; ++ot) {
      uint2 pk;
      pk.x = pack_bf16(acq[ot][0] + bq[ot * 16 + q * 4 + 0] * L2E,
                       acq[ot][1] + bq[ot * 16 + q * 4 + 1] * L2E);
      pk.y = pack_bf16(acq[ot][2] + bq[ot * 16 + q * 4 + 2] * L2E,
                       acq[ot][3] + bq[ot * 16 + q * 4 + 3] * L2E);
      *(uint2*)(qdst + (size_t)n * C8 + ot * 16 + q * 4) = pk;
    }
  } else {
    // ---- K: b = z-12, from xfT (bf16 rows = direct B-frags) ----
    const int b = z - 12;
    const __hip_bfloat16* src = xfT + (size_t)b * NN * CC;
    floatx4 acq[2];
    acq[0] = zf; acq[1] = zf;
    const int n = n0 + w * 16 + li;
#pragma unroll
    for (int kc = 0; kc < 8; ++kc) {
      short8 bfr = *(const short8*)(src + (size_t)n * CC + kc * 32 + q * 8);
#pragma unroll
      for (int ot = 0; ot < 2; ++ot) {
        short8 a = *(const short8*)(WkB + (size_t)(ot * 16 + li) * CC + kc * 32 + q * 8);
        acq[ot] = __builtin_amdgcn_mfma_f32_16x16x32_bf16(a, bfr, acq[ot], 0, 0, 0);
      }
    }
    __hip_bfloat16* kdst = kT + (size_t)b * NN * C8;
#pragma unroll
    for (int ot = 0; ot < 2; ++ot) {
      uint2 pk;
      pk.x = pack_bf16(acq[ot][0] + bk[ot * 16 + q * 4 + 0],
                       acq[ot][1] + bk[ot * 16 + q * 4 + 1]);
      pk.y = pack_bf16(acq[ot][2] + bk[ot * 16 + q * 4 + 2],
                       acq[ot][3] + bk[ot * 16 + q * 4 + 3]);
      *(uint2*)(kdst + (size_t)n * C8 + ot * 16 + q * 4) = pk;
    }
  }
}

// ---------------------------------------------------------------------------
// K3 attn: MFMA flash attention. R4 structure (single V buffer, V loads at
// iter top, one barrier/iter, double-buffered P LDS) with:
//  - i-tile 32 (grid 1536): ~32 fewer VGPRs -> ~4-5 resident blocks/CU so
//    other waves fill the barrier-drain stall. NO launch_bounds min (R5
//    lesson: forcing waves/EU on a register-fat kernel => scratch spills).
//  - row-sums l_i via ones-MFMA on P (matrix pipe) instead of VALU adds +
//    shfl/atomic epilogue; denominator uses the same bf16 P as numerator.
// ---------------------------------------------------------------------------
__global__ void __launch_bounds__(256) attn_kernel(
    const __hip_bfloat16* __restrict__ qT, const __hip_bfloat16* __restrict__ kT,
    const __hip_bfloat16* __restrict__ vB, float* __restrict__ outs) {
  __shared__ uint4 Ps4[2 * 32 * 8];  // 2 x 4KB P buffers, 16B-chunk XOR swizzle
  char* Ps0 = (char*)Ps4;
  const int x_ = blockIdx.x;
  const int wk = (x_ & 7) * 192 + (x_ >> 3);  // contiguous per-XCD work range
  const int g  = wk >> 7;                     // 0..11 (= s*4+b)
  const int i0 = (wk & 127) << 5;             // 32-query tile
  const int b  = g & 3;
  const int t  = threadIdx.x;
  const int w  = t >> 6;
  const int lane = t & 63, q = lane >> 4, li = lane & 15;

  short8 qf[2];
#pragma unroll
  for (int it = 0; it < 2; ++it)
    qf[it] = *(const short8*)(qT + ((size_t)g * NN + i0 + it * 16 + li) * C8 + q * 8);

  short8 ones;
#pragma unroll
  for (int i = 0; i < 8; ++i) ones[i] = (short)0x3F80;  // bf16 1.0

  floatx4 acc[4][2];  // [ct][it]: out^T rows c (w*64+ct*16), cols i
  floatx4 lacc[2];    // ones^T @ P^T : all rows identical = l_i
  floatx4 zf = {0.f, 0.f, 0.f, 0.f};
#pragma unroll
  for (int ct = 0; ct < 4; ++ct)
#pragma unroll
    for (int it = 0; it < 2; ++it) acc[ct][it] = zf;
  lacc[0] = zf; lacc[1] = zf;

  const __hip_bfloat16* kb = kT + (size_t)b * NN * C8;
  const __hip_bfloat16* vb = vB + (size_t)g * CC * NN;
  size_t vrow[4];
#pragma unroll
  for (int ct = 0; ct < 4; ++ct) vrow[ct] = (size_t)(w * 64 + ct * 16 + li) * NN + q * 8;
  const size_t krow = (size_t)(w * 16 + li) * C8 + q * 8;

  short8 kf = *(const short8*)(kb + krow);

  for (int j0 = 0; j0 < NN; j0 += 64) {
    // V frags for this iter (L2-hot): latency hides behind S/exp before barrier
    short8 vf[4][2];
#pragma unroll
    for (int ct = 0; ct < 4; ++ct)
#pragma unroll
      for (int kk = 0; kk < 2; ++kk)
        vf[ct][kk] = *(const short8*)(vb + vrow[ct] + j0 + kk * 32);
    // S^T strip: rows j = j0+w*16+q*4+r, cols i (2 tiles)
    floatx4 st[2];
#pragma unroll
    for (int it = 0; it < 2; ++it)
      st[it] = __builtin_amdgcn_mfma_f32_16x16x32_bf16(kf, qf[it], zf, 0, 0, 0);
    // prefetch next K frag (wraps harmlessly)
    int j0n = (j0 + 64) & (NN - 1);
    kf = *(const short8*)(kb + (size_t)j0n * C8 + krow);
    // exp2 + pack (row-sum comes from ones-MFMA below, not VALU)
    uint2 pk[2];
#pragma unroll
    for (int it = 0; it < 2; ++it) {
      float e0 = fast_exp2(st[it][0]), e1 = fast_exp2(st[it][1]);
      float e2 = fast_exp2(st[it][2]), e3 = fast_exp2(st[it][3]);
      pk[it].x = pack_bf16_fast(e0, e1);
      pk[it].y = pack_bf16_fast(e2, e3);
    }
    char* Ps = Ps0 + ((j0 >> 6) & 1) * 4096;
#pragma unroll
    for (int it = 0; it < 2; ++it) {
      int row = it * 16 + li;
      int chunk = (w * 2 + (q >> 1)) ^ (row & 7);
      *(uint2*)(Ps + row * 128 + chunk * 16 + (q & 1) * 8) = pk[it];  // b64
    }
    __syncthreads();  // P[buf] visible; prior-iter reads of this buf long done
#pragma unroll
    for (int kk = 0; kk < 2; ++kk) {
      short8 pf[2];
#pragma unroll
      for (int it = 0; it < 2; ++it) {
        int row = it * 16 + li;
        int chunk = (kk * 4 + q) ^ (row & 7);
        pf[it] = *(const short8*)(Ps + row * 128 + chunk * 16);
      }
#pragma unroll
      for (int it = 0; it < 2; ++it)
        lacc[it] = __builtin_amdgcn_mfma_f32_16x16x32_bf16(ones, pf[it],
                                                           lacc[it], 0, 0, 0);
#pragma unroll
      for (int ct = 0; ct < 4; ++ct)
#pragma unroll
        for (int it = 0; it < 2; ++it)
          acc[ct][it] = __builtin_amdgcn_mfma_f32_16x16x32_bf16(
              vf[ct][kk], pf[it], acc[ct][it], 0, 0, 0);
    }
  }
  float inv[2];
#pragma unroll
  for (int it = 0; it < 2; ++it) inv[it] = 1.0f / lacc[it][0];
  float* ob = outs + (size_t)b * CC * NN + i0;
#pragma unroll
  for (int ct = 0; ct < 4; ++ct)
#pragma unroll
    for (int it = 0; it < 2; ++it)
#pragma unroll
      for (int r = 0; r < 4; ++r) {
        int c = w * 64 + ct * 16 + q * 4 + r;
        atomicAdd(ob + (size_t)c * NN + it * 16 + li, acc[ct][it][r] * inv[it]);
      }
}

// ---------------------------------------------------------------------------
// K4 final (T2 fused): stage outs[b][:, n0:n0+64] fp32 * gamma -> LDS bf16
// [n][c], then out[b][o][n] = WfB[:, :256] @ LDS + WfB[:, 256:] @ xfT + bf.
// ---------------------------------------------------------------------------
__global__ void __launch_bounds__(256) final_kernel(
    const float* __restrict__ outs, const __hip_bfloat16* __restrict__ xfT,
    const __hip_bfloat16* __restrict__ WfB, const float* __restrict__ bfv,
    const float* __restrict__ gp, float* __restrict__ out) {
  __shared__ unsigned xs32[64][129];
  const int b = blockIdx.y, n0 = blockIdx.x * 64;
  const int t = threadIdx.x, w = t >> 6, lane = t & 63;
  const int q = lane >> 4, li = lane & 15;
  const float gm = gp[0];
  floatx4 zf = {0.f, 0.f, 0.f, 0.f};
  // stage gamma*outs
  {
    const float* Og = outs + (size_t)b * CC * NN + n0;
    const int n4 = (t & 15) * 4, pb = t >> 4;
#pragma unroll
    for (int m = 0; m < 8; ++m) {
      int p = pb + m * 16;
      int c = 2 * p;
      float4 a = *(const float4*)(Og + (size_t)c * NN + n4);
      float4 bq4 = *(const float4*)(Og + (size_t)(c + 1) * NN + n4);
      xs32[n4 + 0][p] = pack_bf16(a.x * gm, bq4.x * gm);
      xs32[n4 + 1][p] = pack_bf16(a.y * gm, bq4.y * gm);
      xs32[n4 + 2][p] = pack_bf16(a.z * gm, bq4.z * gm);
      xs32[n4 + 3][p] = pack_bf16(a.w * gm, bq4.w * gm);
    }
  }
  __syncthreads();
  const __hip_bfloat16* xT = xfT + (size_t)b * NN * CC;
  const int o_w = w * 64;
  floatx4 acc[4][4];
#pragma unroll
  for (int ot = 0; ot < 4; ++ot)
#pragma unroll
    for (int nt = 0; nt < 4; ++nt) acc[ot][nt] = zf;
#pragma unroll
  for (int kc = 0; kc < 16; ++kc) {
    short8 a[4], bfr[4];
#pragma unroll
    for (int ot = 0; ot < 4; ++ot)
      a[ot] = *(const short8*)(WfB + (size_t)(o_w + ot * 16 + li) * (2 * CC) +
                               kc * 32 + q * 8);
    if (kc < 8) {
#pragma unroll
      for (int nt = 0; nt < 4; ++nt)
        bfr[nt] = *(const short8*)&xs32[nt * 16 + li][kc * 16 + q * 4];
    } else {
#pragma unroll
      for (int nt = 0; nt < 4; ++nt)
        bfr[nt] = *(const short8*)(xT + (size_t)(n0 + nt * 16 + li) * CC +
                                   (kc - 8) * 32 + q * 8);
    }
#pragma unroll
    for (int ot = 0; ot < 4; ++ot)
#pragma unroll
      for (int nt = 0; nt < 4; ++nt)
        acc[ot][nt] = __builtin_amdgcn_mfma_f32_16x16x32_bf16(a[ot], bfr[nt],
                                                              acc[ot][nt], 0, 0, 0);
  }
  float* ob = out + (size_t)b * CC * NN;
#pragma unroll
  for (int ot = 0; ot < 4; ++ot)
#pragma unroll
    for (int r = 0; r < 4; ++r) {
      int o = o_w + ot * 16 + q * 4 + r;
      float bo = bfv[o];
#pragma unroll
      for (int nt = 0; nt < 4; ++nt)
        ob[(size_t)o * NN + n0 + nt * 16 + li] = acc[ot][nt][r] + bo;
    }
}

// ---------------------------------------------------------------------------
extern "C" void kernel_launch(void* const* d_in, const int* in_sizes, int n_in,
                              void* d_out, int out_size, void* d_ws,
                              size_t ws_size, hipStream_t stream) {
  const float* x_f = (const float*)d_in[0];
  const float* x_b = (const float*)d_in[1];
  const float* Wq  = (const float*)d_in[2];
  const float* bq  = (const float*)d_in[3];
  const float* Wk  = (const float*)d_in[4];
  const float* bk  = (const float*)d_in[5];
  const float* Wv  = (const float*)d_in[6];
  const float* bv  = (const float*)d_in[7];
  const float* Wf  = (const float*)d_in[8];
  const float* bf  = (const float*)d_in[9];
  const float* gm  = (const float*)d_in[10];
  float* out = (float*)d_out;

  // workspace layout (~53 MB)
  char* ws = (char*)d_ws;
  __hip_bfloat16* vB  = (__hip_bfloat16*)ws;                        // 24 MB [12][256][4096]
  float*          outs = (float*)(ws + ((size_t)24 << 20));         // 16 MB [4][256][4096]
  __hip_bfloat16* xfT = (__hip_bfloat16*)(ws + ((size_t)40 << 20)); //  8 MB [4][4096][256]
  __hip_bfloat16* qT  = (__hip_bfloat16*)(ws + ((size_t)48 << 20)); //  3 MB [12][4096][32]
  __hip_bfloat16* kT  = (__hip_bfloat16*)(ws + ((size_t)51 << 20)); //  1 MB [4][4096][32]
  __hip_bfloat16* WqB = (__hip_bfloat16*)(ws + ((size_t)52 << 20)); // 16 KB
  __hip_bfloat16* WkB = WqB + 8192;                                 // 16 KB
  __hip_bfloat16* WvB = WkB + 8192;                                 // 128 KB
  __hip_bfloat16* WfB = WvB + 65536;                                // 256 KB

  hipLaunchKernelGGL(pre_kernel, dim3(NN / 64, CC / 64, 5), dim3(256), 0,
                     stream, x_f, xfT, (float4*)outs, Wq, Wk, Wv, Wf, WqB, WkB,
                     WvB, WfB);
  hipLaunchKernelGGL(qkv_kernel, dim3(NN / 64, 16), dim3(256), 0, stream,
                     x_b, xfT, WqB, WkB, WvB, bq, bk, bv, qT, kT, vB);
  hipLaunchKernelGGL(attn_kernel, dim3(1536), dim3(256), 0, stream,
                     qT, kT, vB, outs);
  hipLaunchKernelGGL(final_kernel, dim3(NN / 64, BB), dim3(256), 0, stream,
                     outs, xfT, WfB, bf, gm, out);
}

// Round 7
// 418.834 us; speedup vs baseline: 1.2721x; 1.2721x over previous
//
#include <hip/hip_runtime.h>
#include <hip/hip_bf16.h>

#define BB 4
#define CC 256
#define NN 4096
#define SS 3
#define C8 32
#define L2E 1.4426950408889634f

typedef __attribute__((ext_vector_type(8))) short short8;
typedef __attribute__((ext_vector_type(4))) float floatx4;
typedef __attribute__((ext_vector_type(16))) float floatx16;

static __device__ inline unsigned pack_bf16(float a, float b) {  // RNE (projections)
  union { __hip_bfloat16 h; unsigned short u; } ua, ub;
  ua.h = __float2bfloat16(a);
  ub.h = __float2bfloat16(b);
  return ((unsigned)ub.u << 16) | (unsigned)ua.u;
}

static __device__ inline unsigned pack_bf16_fast(float a, float b) {  // round-half-up (P only)
  unsigned ua = __float_as_uint(a), ub = __float_as_uint(b);
  return ((ua + 0x8000u) >> 16) | ((ub + 0x8000u) & 0xffff0000u);
}

static __device__ inline float fast_exp2(float x) {
#if __has_builtin(__builtin_amdgcn_exp2f)
  return __builtin_amdgcn_exp2f(x);
#else
  return exp2f(x);
#endif
}

// ---------------------------------------------------------------------------
// K1 pre: z<4: xfT[z][n][c] = bf16(x_f[z][c][n])  (64x64 LDS transpose)
//         z==4: zero outs + weights fp32->bf16 (Wq scaled by log2e)
// ---------------------------------------------------------------------------
__global__ void __launch_bounds__(256) pre_kernel(
    const float* __restrict__ xf, __hip_bfloat16* __restrict__ xfT,
    float4* __restrict__ outs4, const float* __restrict__ Wq,
    const float* __restrict__ Wk, const float* __restrict__ Wv,
    const float* __restrict__ Wf, __hip_bfloat16* __restrict__ WqB,
    __hip_bfloat16* __restrict__ WkB, __hip_bfloat16* __restrict__ WvB,
    __hip_bfloat16* __restrict__ WfB) {
  const int z = blockIdx.z, t = threadIdx.x;
  if (z < 4) {
    __shared__ float ts[64][65];
    const int c0 = blockIdx.y * 64, n0 = blockIdx.x * 64;
    const float* Xg = xf + ((size_t)z * CC + c0) * NN + n0;
    for (int idx = t; idx < 64 * 64; idx += 256) {
      int r = idx >> 6, qq = idx & 63;
      ts[r][qq] = Xg[(size_t)r * NN + qq];
    }
    __syncthreads();
    __hip_bfloat16* og = xfT + (size_t)z * NN * CC + (size_t)n0 * CC + c0;
    for (int idx = t; idx < 64 * 32; idx += 256) {
      int n = idx >> 5, pc = idx & 31;
      ((unsigned*)(og + (size_t)n * CC))[pc] =
          pack_bf16(ts[2 * pc][n], ts[2 * pc + 1][n]);
    }
  } else {
    const int wb = blockIdx.y * 64 + blockIdx.x;  // 0..255
    float4 zq = {0.f, 0.f, 0.f, 0.f};
#pragma unroll
    for (int k = 0; k < 16; ++k) outs4[(size_t)wb * 4096 + k * 256 + t] = zq;
#pragma unroll
    for (int k = 0; k < 4; ++k) {
      int idx = wb * 1024 + k * 256 + t;
      if (idx < 8192) WqB[idx] = __float2bfloat16(Wq[idx] * L2E);
      else if (idx < 16384) WkB[idx - 8192] = __float2bfloat16(Wk[idx - 8192]);
      else if (idx < 81920) WvB[idx - 16384] = __float2bfloat16(Wv[idx - 16384]);
      else if (idx < 212992) WfB[idx - 81920] = __float2bfloat16(Wf[idx - 81920]);
    }
  }
}

// ---------------------------------------------------------------------------
// K2 qkv: z<12 -> g=z: stage x_b[g][:, n0:n0+64] fp32 -> LDS bf16 [n][c],
//   then MFMA: vB[g] (Wv, all waves, c-split) and qT[g] (Wq, wave->n-quarter).
// z>=12 -> b=z-12: kT[b] from xfT rows (direct global B-frags, no LDS).
// ---------------------------------------------------------------------------
__global__ void __launch_bounds__(256) qkv_kernel(
    const float* __restrict__ xb, const __hip_bfloat16* __restrict__ xfT,
    const __hip_bfloat16* __restrict__ WqB, const __hip_bfloat16* __restrict__ WkB,
    const __hip_bfloat16* __restrict__ WvB, const float* __restrict__ bq,
    const float* __restrict__ bk, const float* __restrict__ bv,
    __hip_bfloat16* __restrict__ qT, __hip_bfloat16* __restrict__ kT,
    __hip_bfloat16* __restrict__ vB) {
  __shared__ unsigned xs32[64][129];  // [n][c-pair] bf16x2, +1 dword pad
  const int z = blockIdx.y, n0 = blockIdx.x * 64;
  const int t = threadIdx.x, w = t >> 6, lane = t & 63;
  const int q = lane >> 4, li = lane & 15;
  floatx4 zf = {0.f, 0.f, 0.f, 0.f};

  if (z < 12) {
    const int g = z;
    const float* Xg = xb + (size_t)g * CC * NN + n0;
    const int n4 = (t & 15) * 4, pb = t >> 4;
#pragma unroll
    for (int m = 0; m < 8; ++m) {
      int p = pb + m * 16;          // c-pair 0..127
      int c = 2 * p;
      float4 a = *(const float4*)(Xg + (size_t)c * NN + n4);
      float4 bq4 = *(const float4*)(Xg + (size_t)(c + 1) * NN + n4);
      xs32[n4 + 0][p] = pack_bf16(a.x, bq4.x);
      xs32[n4 + 1][p] = pack_bf16(a.y, bq4.y);
      xs32[n4 + 2][p] = pack_bf16(a.z, bq4.z);
      xs32[n4 + 3][p] = pack_bf16(a.w, bq4.w);
    }
    __syncthreads();
    // ---- V: wave w -> c-out strip w*64, all 4 n-tiles ----
    const int o_w = w * 64;
    floatx4 acc[4][4];
#pragma unroll
    for (int ot = 0; ot < 4; ++ot)
#pragma unroll
      for (int nt = 0; nt < 4; ++nt) acc[ot][nt] = zf;
#pragma unroll
    for (int kc = 0; kc < 8; ++kc) {
      short8 a[4], bfr[4];
#pragma unroll
      for (int ot = 0; ot < 4; ++ot)
        a[ot] = *(const short8*)(WvB + (size_t)(o_w + ot * 16 + li) * CC + kc * 32 + q * 8);
#pragma unroll
      for (int nt = 0; nt < 4; ++nt)
        bfr[nt] = *(const short8*)&xs32[nt * 16 + li][kc * 16 + q * 4];
#pragma unroll
      for (int ot = 0; ot < 4; ++ot)
#pragma unroll
        for (int nt = 0; nt < 4; ++nt)
          acc[ot][nt] = __builtin_amdgcn_mfma_f32_16x16x32_bf16(a[ot], bfr[nt],
                                                                acc[ot][nt], 0, 0, 0);
    }
    __hip_bfloat16* dst = vB + (size_t)g * CC * NN;
#pragma unroll
    for (int ot = 0; ot < 4; ++ot)
#pragma unroll
      for (int r = 0; r < 4; ++r) {
        int o = o_w + ot * 16 + q * 4 + r;
        float bo = bv[o];
#pragma unroll
        for (int nt = 0; nt < 4; ++nt)
          dst[(size_t)o * NN + n0 + nt * 16 + li] =
              __float2bfloat16(acc[ot][nt][r] + bo);
      }
    // ---- Q: wave w -> n-tile w ----
    floatx4 acq[2];
    acq[0] = zf; acq[1] = zf;
#pragma unroll
    for (int kc = 0; kc < 8; ++kc) {
      short8 bfr = *(const short8*)&xs32[w * 16 + li][kc * 16 + q * 4];
#pragma unroll
      for (int ot = 0; ot < 2; ++ot) {
        short8 a = *(const short8*)(WqB + (size_t)(ot * 16 + li) * CC + kc * 32 + q * 8);
        acq[ot] = __builtin_amdgcn_mfma_f32_16x16x32_bf16(a, bfr, acq[ot], 0, 0, 0);
      }
    }
    __hip_bfloat16* qdst = qT + (size_t)g * NN * C8;
    int n = n0 + w * 16 + li;
#pragma unroll
    for (int ot = 0; ot < 2; ++ot) {
      uint2 pk;
      pk.x = pack_bf16(acq[ot][0] + bq[ot * 16 + q * 4 + 0] * L2E,
                       acq[ot][1] + bq[ot * 16 + q * 4 + 1] * L2E);
      pk.y = pack_bf16(acq[ot][2] + bq[ot * 16 + q * 4 + 2] * L2E,
                       acq[ot][3] + bq[ot * 16 + q * 4 + 3] * L2E);
      *(uint2*)(qdst + (size_t)n * C8 + ot * 16 + q * 4) = pk;
    }
  } else {
    const int b = z - 12;
    const __hip_bfloat16* src = xfT + (size_t)b * NN * CC;
    floatx4 acq[2];
    acq[0] = zf; acq[1] = zf;
    const int n = n0 + w * 16 + li;
#pragma unroll
    for (int kc = 0; kc < 8; ++kc) {
      short8 bfr = *(const short8*)(src + (size_t)n * CC + kc * 32 + q * 8);
#pragma unroll
      for (int ot = 0; ot < 2; ++ot) {
        short8 a = *(const short8*)(WkB + (size_t)(ot * 16 + li) * CC + kc * 32 + q * 8);
        acq[ot] = __builtin_amdgcn_mfma_f32_16x16x32_bf16(a, bfr, acq[ot], 0, 0, 0);
      }
    }
    __hip_bfloat16* kdst = kT + (size_t)b * NN * C8;
#pragma unroll
    for (int ot = 0; ot < 2; ++ot) {
      uint2 pk;
      pk.x = pack_bf16(acq[ot][0] + bk[ot * 16 + q * 4 + 0],
                       acq[ot][1] + bk[ot * 16 + q * 4 + 1]);
      pk.y = pack_bf16(acq[ot][2] + bk[ot * 16 + q * 4 + 2],
                       acq[ot][3] + bk[ot * 16 + q * 4 + 3]);
      *(uint2*)(kdst + (size_t)n * C8 + ot * 16 + q * 4) = pk;
    }
  }
}

// ---------------------------------------------------------------------------
// K3 attn: wave-independent flash attention, 32x32x16 MFMA, ZERO LDS, ZERO
// __syncthreads. Block = (g, 64-query i-tile); wave w owns c-strip w*64.
// Each wave redundantly computes S^T (32x32 tiles) for the shared i-tile;
// P goes from S's C/D layout to PV's B-frag layout via 4 shfl_xor(32) per
// tile (register lane-pair exchange) -- no LDS round-trip, no barrier.
//   S^T C/D:  col i = lane&31, row j = (r&3)+8*(r>>2)+4h   (h = lane>>5)
//   B-frag:   lane needs k = 8h+0..7  -> swap half the dwords with lane^32
// ---------------------------------------------------------------------------
__global__ void __launch_bounds__(256) attn_kernel(
    const __hip_bfloat16* __restrict__ qT, const __hip_bfloat16* __restrict__ kT,
    const __hip_bfloat16* __restrict__ vB, float* __restrict__ outs) {
  const int x_ = blockIdx.x;
  const int wk = (x_ & 7) * 96 + (x_ >> 3);  // contiguous per-XCD work range
  const int g  = wk >> 6;                    // 0..11 (= s*4+b)
  const int i0 = (wk & 63) << 6;             // 64-query tile
  const int b  = g & 3;
  const int t  = threadIdx.x;
  const int w  = t >> 6;                     // c-strip w*64
  const int lane = t & 63, m = lane & 31, h = lane >> 5;
  const int cw = w * 64;

  const __hip_bfloat16* kb = kT + (size_t)b * NN * C8;
  const __hip_bfloat16* vb = vB + (size_t)g * CC * NN;

  // persistent Q B-frags: qf[it][hf] = Q[i0+it*32+m][hf*16 + 8h + 0..7]
  short8 qf[2][2];
#pragma unroll
  for (int it = 0; it < 2; ++it)
#pragma unroll
    for (int hf = 0; hf < 2; ++hf)
      qf[it][hf] = *(const short8*)(qT + ((size_t)g * NN + i0 + it * 32 + m) * C8 +
                                    hf * 16 + 8 * h);

  floatx16 acc[2][2];  // [ct][it]: out^T rows c=cw+ct*32+row, cols i
#pragma unroll
  for (int ct = 0; ct < 2; ++ct)
#pragma unroll
    for (int it = 0; it < 2; ++it)
#pragma unroll
      for (int r = 0; r < 16; ++r) acc[ct][it][r] = 0.f;
  float rsum[2] = {0.f, 0.f};

  const size_t krow  = (size_t)m * C8 + 8 * h;
  const size_t vrow0 = (size_t)(cw + m) * NN + 8 * h;
  const size_t vrow1 = (size_t)(cw + 32 + m) * NN + 8 * h;

#pragma unroll 1
  for (int j0 = 0; j0 < NN; j0 += 32) {
    // loads for this iter (no barrier anywhere: waits are per-consumer)
    short8 kf0  = *(const short8*)(kb + (size_t)j0 * C8 + krow);
    short8 kf1  = *(const short8*)(kb + (size_t)j0 * C8 + krow + 16);
    short8 vf00 = *(const short8*)(vb + vrow0 + j0);
    short8 vf01 = *(const short8*)(vb + vrow0 + j0 + 16);
    short8 vf10 = *(const short8*)(vb + vrow1 + j0);
    short8 vf11 = *(const short8*)(vb + vrow1 + j0 + 16);

    // S^T 32x32 tiles (rows j, cols i), K=32 via two chained x16 MFMAs
    floatx16 st[2];
#pragma unroll
    for (int it = 0; it < 2; ++it) {
      floatx16 s;
#pragma unroll
      for (int r = 0; r < 16; ++r) s[r] = 0.f;
      s = __builtin_amdgcn_mfma_f32_32x32x16_bf16(kf0, qf[it][0], s, 0, 0, 0);
      s = __builtin_amdgcn_mfma_f32_32x32x16_bf16(kf1, qf[it][1], s, 0, 0, 0);
      st[it] = s;
    }

    // exp2 + row-sum + pack + lane-pair exchange -> PV B-frags
    short8 pf[2][2];
#pragma unroll
    for (int it = 0; it < 2; ++it) {
      float e[16];
      float ps = 0.f;
#pragma unroll
      for (int r = 0; r < 16; ++r) {
        e[r] = fast_exp2(st[it][r]);
        ps += e[r];
      }
      rsum[it] += ps;
      unsigned d[8];
#pragma unroll
      for (int p = 0; p < 8; ++p) d[p] = pack_bf16_fast(e[2 * p], e[2 * p + 1]);
      unsigned ra = __shfl_xor(h ? d[0] : d[2], 32, 64);
      unsigned rb = __shfl_xor(h ? d[1] : d[3], 32, 64);
      unsigned rc = __shfl_xor(h ? d[4] : d[6], 32, 64);
      unsigned rd = __shfl_xor(h ? d[5] : d[7], 32, 64);
      uint4 f0 = (h == 0) ? uint4{d[0], d[1], ra, rb} : uint4{ra, rb, d[2], d[3]};
      uint4 f1 = (h == 0) ? uint4{d[4], d[5], rc, rd} : uint4{rc, rd, d[6], d[7]};
      pf[it][0] = *(short8*)&f0;
      pf[it][1] = *(short8*)&f1;
    }

    // PV: acc[ct][it] += V^T * P^T   (K=32 via two x16 MFMAs)
#pragma unroll
    for (int it = 0; it < 2; ++it) {
      acc[0][it] = __builtin_amdgcn_mfma_f32_32x32x16_bf16(vf00, pf[it][0], acc[0][it], 0, 0, 0);
      acc[0][it] = __builtin_amdgcn_mfma_f32_32x32x16_bf16(vf01, pf[it][1], acc[0][it], 0, 0, 0);
      acc[1][it] = __builtin_amdgcn_mfma_f32_32x32x16_bf16(vf10, pf[it][0], acc[1][it], 0, 0, 0);
      acc[1][it] = __builtin_amdgcn_mfma_f32_32x32x16_bf16(vf11, pf[it][1], acc[1][it], 0, 0, 0);
    }
  }

  // l_i: lane's rsum covers its j-subset; lane^32 has the complement
  float inv[2];
#pragma unroll
  for (int it = 0; it < 2; ++it) {
    float v = rsum[it] + __shfl_xor(rsum[it], 32, 64);
    inv[it] = 1.0f / v;
  }
  // accumulate: c = cw + ct*32 + (r&3)+8*(r>>2)+4h, i = i0 + it*32 + m
  float* ob = outs + (size_t)b * CC * NN + i0;
#pragma unroll
  for (int ct = 0; ct < 2; ++ct)
#pragma unroll
    for (int it = 0; it < 2; ++it)
#pragma unroll
      for (int r = 0; r < 16; ++r) {
        int c = cw + ct * 32 + (r & 3) + 8 * (r >> 2) + 4 * h;
        atomicAdd(ob + (size_t)c * NN + it * 32 + m, acc[ct][it][r] * inv[it]);
      }
}

// ---------------------------------------------------------------------------
// K4 final (T2 fused): stage outs[b][:, n0:n0+64] fp32 * gamma -> LDS bf16
// [n][c], then out[b][o][n] = WfB[:, :256] @ LDS + WfB[:, 256:] @ xfT + bf.
// ---------------------------------------------------------------------------
__global__ void __launch_bounds__(256) final_kernel(
    const float* __restrict__ outs, const __hip_bfloat16* __restrict__ xfT,
    const __hip_bfloat16* __restrict__ WfB, const float* __restrict__ bfv,
    const float* __restrict__ gp, float* __restrict__ out) {
  __shared__ unsigned xs32[64][129];
  const int b = blockIdx.y, n0 = blockIdx.x * 64;
  const int t = threadIdx.x, w = t >> 6, lane = t & 63;
  const int q = lane >> 4, li = lane & 15;
  const float gm = gp[0];
  floatx4 zf = {0.f, 0.f, 0.f, 0.f};
  {
    const float* Og = outs + (size_t)b * CC * NN + n0;
    const int n4 = (t & 15) * 4, pb = t >> 4;
#pragma unroll
    for (int m = 0; m < 8; ++m) {
      int p = pb + m * 16;
      int c = 2 * p;
      float4 a = *(const float4*)(Og + (size_t)c * NN + n4);
      float4 bq4 = *(const float4*)(Og + (size_t)(c + 1) * NN + n4);
      xs32[n4 + 0][p] = pack_bf16(a.x * gm, bq4.x * gm);
      xs32[n4 + 1][p] = pack_bf16(a.y * gm, bq4.y * gm);
      xs32[n4 + 2][p] = pack_bf16(a.z * gm, bq4.z * gm);
      xs32[n4 + 3][p] = pack_bf16(a.w * gm, bq4.w * gm);
    }
  }
  __syncthreads();
  const __hip_bfloat16* xT = xfT + (size_t)b * NN * CC;
  const int o_w = w * 64;
  floatx4 acc[4][4];
#pragma unroll
  for (int ot = 0; ot < 4; ++ot)
#pragma unroll
    for (int nt = 0; nt < 4; ++nt) acc[ot][nt] = zf;
#pragma unroll
  for (int kc = 0; kc < 16; ++kc) {
    short8 a[4], bfr[4];
#pragma unroll
    for (int ot = 0; ot < 4; ++ot)
      a[ot] = *(const short8*)(WfB + (size_t)(o_w + ot * 16 + li) * (2 * CC) +
                               kc * 32 + q * 8);
    if (kc < 8) {
#pragma unroll
      for (int nt = 0; nt < 4; ++nt)
        bfr[nt] = *(const short8*)&xs32[nt * 16 + li][kc * 16 + q * 4];
    } else {
#pragma unroll
      for (int nt = 0; nt < 4; ++nt)
        bfr[nt] = *(const short8*)(xT + (size_t)(n0 + nt * 16 + li) * CC +
                                   (kc - 8) * 32 + q * 8);
    }
#pragma unroll
    for (int ot = 0; ot < 4; ++ot)
#pragma unroll
      for (int nt = 0; nt < 4; ++nt)
        acc[ot][nt] = __builtin_amdgcn_mfma_f32_16x16x32_bf16(a[ot], bfr[nt],
                                                              acc[ot][nt], 0, 0, 0);
  }
  float* ob = out + (size_t)b * CC * NN;
#pragma unroll
  for (int ot = 0; ot < 4; ++ot)
#pragma unroll
    for (int r = 0; r < 4; ++r) {
      int o = o_w + ot * 16 + q * 4 + r;
      float bo = bfv[o];
#pragma unroll
      for (int nt = 0; nt < 4; ++nt)
        ob[(size_t)o * NN + n0 + nt * 16 + li] = acc[ot][nt][r] + bo;
    }
}

// ---------------------------------------------------------------------------
extern "C" void kernel_launch(void* const* d_in, const int* in_sizes, int n_in,
                              void* d_out, int out_size, void* d_ws,
                              size_t ws_size, hipStream_t stream) {
  const float* x_f = (const float*)d_in[0];
  const float* x_b = (const float*)d_in[1];
  const float* Wq  = (const float*)d_in[2];
  const float* bq  = (const float*)d_in[3];
  const float* Wk  = (const float*)d_in[4];
  const float* bk  = (const float*)d_in[5];
  const float* Wv  = (const float*)d_in[6];
  const float* bv  = (const float*)d_in[7];
  const float* Wf  = (const float*)d_in[8];
  const float* bf  = (const float*)d_in[9];
  const float* gm  = (const float*)d_in[10];
  float* out = (float*)d_out;

  // workspace layout (~53 MB)
  char* ws = (char*)d_ws;
  __hip_bfloat16* vB  = (__hip_bfloat16*)ws;                        // 24 MB [12][256][4096]
  float*          outs = (float*)(ws + ((size_t)24 << 20));         // 16 MB [4][256][4096]
  __hip_bfloat16* xfT = (__hip_bfloat16*)(ws + ((size_t)40 << 20)); //  8 MB [4][4096][256]
  __hip_bfloat16* qT  = (__hip_bfloat16*)(ws + ((size_t)48 << 20)); //  3 MB [12][4096][32]
  __hip_bfloat16* kT  = (__hip_bfloat16*)(ws + ((size_t)51 << 20)); //  1 MB [4][4096][32]
  __hip_bfloat16* WqB = (__hip_bfloat16*)(ws + ((size_t)52 << 20)); // 16 KB
  __hip_bfloat16* WkB = WqB + 8192;                                 // 16 KB
  __hip_bfloat16* WvB = WkB + 8192;                                 // 128 KB
  __hip_bfloat16* WfB = WvB + 65536;                                // 256 KB

  hipLaunchKernelGGL(pre_kernel, dim3(NN / 64, CC / 64, 5), dim3(256), 0,
                     stream, x_f, xfT, (float4*)outs, Wq, Wk, Wv, Wf, WqB, WkB,
                     WvB, WfB);
  hipLaunchKernelGGL(qkv_kernel, dim3(NN / 64, 16), dim3(256), 0, stream,
                     x_b, xfT, WqB, WkB, WvB, bq, bk, bv, qT, kT, vB);
  hipLaunchKernelGGL(attn_kernel, dim3(768), dim3(256), 0, stream,
                     qT, kT, vB, outs);
  hipLaunchKernelGGL(final_kernel, dim3(NN / 64, BB), dim3(256), 0, stream,
                     outs, xfT, WfB, bf, gm, out);
}